// Round 3
// baseline (2388.977 us; speedup 1.0000x reference)
//
#include <hip/hip_runtime.h>

#define NN 16384
#define DD 32
#define TPB1 256
#define ROWS_PER_BLK 256
#define UNROLL 8
#define TPB2 64

typedef int ivec4 __attribute__((ext_vector_type(4)));

// ---------------- K1: streaming scan of adj (int4/lane), fire-and-forget atomics
// agg[i][:] += x[j][:] for each nonzero adj[j][i]
__global__ __launch_bounds__(TPB1) void k_agg(const int* __restrict__ adj,
                                              const float* __restrict__ x,
                                              float* __restrict__ agg) {
  const int tcol = blockIdx.x * TPB1 + threadIdx.x;  // ivec4 index (4 cols/thread)
  const int j0 = blockIdx.y * ROWS_PER_BLK;
  const ivec4* base = (const ivec4*)adj;
  for (int jj = 0; jj < ROWS_PER_BLK; jj += UNROLL) {
    ivec4 v[UNROLL];
#pragma unroll
    for (int u = 0; u < UNROLL; ++u)
      v[u] = __builtin_nontemporal_load(base + (size_t)(j0 + jj + u) * (NN / 4) + tcol);
#pragma unroll
    for (int u = 0; u < UNROLL; ++u) {
      if (v[u].x | v[u].y | v[u].z | v[u].w) {   // rare: ~0.8% per lane
        const float4* xr = (const float4*)(x + (size_t)(j0 + jj + u) * DD);
        int comp[4] = {v[u].x, v[u].y, v[u].z, v[u].w};
#pragma unroll
        for (int k = 0; k < 4; ++k) {
          if (comp[k]) {
            float* dst = agg + (size_t)(tcol * 4 + k) * DD;
#pragma unroll
            for (int q = 0; q < 8; ++q) {
              float4 xv = xr[q];
              atomicAdd(dst + 4 * q + 0, xv.x);
              atomicAdd(dst + 4 * q + 1, xv.y);
              atomicAdd(dst + 4 * q + 2, xv.z);
              atomicAdd(dst + 4 * q + 3, xv.w);
            }
          }
        }
      }
    }
  }
}

// ---------------- K2: h1 = (x + agg)@W1 + b1; BN sum/sumsq via wave butterfly + atomics
__global__ __launch_bounds__(TPB2) void k_mlp1(const float* __restrict__ x,
                                               const float* __restrict__ agg,
                                               const float* __restrict__ W1,
                                               const float* __restrict__ b1,
                                               float* __restrict__ h1,
                                               float* __restrict__ stats) {
  __shared__ float sW[DD * DD];
  __shared__ float sb[DD];
  for (int t = threadIdx.x; t < DD * DD; t += TPB2) sW[t] = W1[t];
  if (threadIdx.x < DD) sb[threadIdx.x] = b1[threadIdx.x];
  __syncthreads();
  const int i = blockIdx.x * TPB2 + threadIdx.x;
  float hin[DD];
  const float4* xr = (const float4*)(x + (size_t)i * DD);
  const float4* ar = (const float4*)(agg + (size_t)i * DD);
#pragma unroll
  for (int q = 0; q < 8; ++q) {
    float4 v = xr[q], a = ar[q];
    hin[4*q]   = v.x + a.x; hin[4*q+1] = v.y + a.y;
    hin[4*q+2] = v.z + a.z; hin[4*q+3] = v.w + a.w;
  }
  float h[DD];
#pragma unroll
  for (int d = 0; d < DD; ++d) h[d] = sb[d];
  const float4* sW4 = (const float4*)sW;
#pragma unroll 4
  for (int k = 0; k < DD; ++k) {
    float hk = hin[k];
#pragma unroll
    for (int q = 0; q < 8; ++q) {
      float4 w = sW4[k*8 + q];
      h[4*q+0] += hk*w.x; h[4*q+1] += hk*w.y;
      h[4*q+2] += hk*w.z; h[4*q+3] += hk*w.w;
    }
  }
  float4* hw = (float4*)(h1 + (size_t)i * DD);
#pragma unroll
  for (int q = 0; q < 8; ++q)
    hw[q] = make_float4(h[4*q], h[4*q+1], h[4*q+2], h[4*q+3]);
#pragma unroll
  for (int d = 0; d < DD; ++d) {
    float s = h[d], ss = h[d] * h[d];
#pragma unroll
    for (int off = 32; off > 0; off >>= 1) {
      s += __shfl_xor(s, off);
      ss += __shfl_xor(ss, off);
    }
    if (threadIdx.x == 0) {
      atomicAdd(&stats[d], s);
      atomicAdd(&stats[DD + d], ss);
    }
  }
}

// ---------------- K3: fold BN stats into scale/shift
__global__ void k_bn(const float* __restrict__ gamma, const float* __restrict__ beta,
                     float* __restrict__ stats) {
  int d = threadIdx.x;
  if (d < DD) {
    float mu = stats[d] * (1.0f / NN);
    float var = stats[DD + d] * (1.0f / NN) - mu * mu;
    float sc = gamma[d] * rsqrtf(var + 1e-5f);
    stats[96 + d] = sc;                 // scale
    stats[128 + d] = beta[d] - mu * sc; // shift
  }
}

// ---------------- K4: hn = relu(h1*sc+sh); h2 = relu(hn@W2+b2); pool += sum(h2)
__global__ __launch_bounds__(TPB2) void k_mlp2(const float* __restrict__ h1,
                                               const float* __restrict__ W2,
                                               const float* __restrict__ b2,
                                               float* __restrict__ stats) {
  __shared__ float sW[DD * DD];
  __shared__ float sb[DD], ssc[DD], ssh[DD];
  for (int t = threadIdx.x; t < DD * DD; t += TPB2) sW[t] = W2[t];
  if (threadIdx.x < DD) {
    sb[threadIdx.x] = b2[threadIdx.x];
    ssc[threadIdx.x] = stats[96 + threadIdx.x];
    ssh[threadIdx.x] = stats[128 + threadIdx.x];
  }
  __syncthreads();
  const int i = blockIdx.x * TPB2 + threadIdx.x;
  float hn[DD];
  const float4* hr = (const float4*)(h1 + (size_t)i * DD);
#pragma unroll
  for (int q = 0; q < 8; ++q) {
    float4 v = hr[q];
    hn[4*q] = v.x; hn[4*q+1] = v.y; hn[4*q+2] = v.z; hn[4*q+3] = v.w;
  }
#pragma unroll
  for (int d = 0; d < DD; ++d) hn[d] = fmaxf(hn[d] * ssc[d] + ssh[d], 0.f);
  float h[DD];
#pragma unroll
  for (int d = 0; d < DD; ++d) h[d] = sb[d];
  const float4* sW4 = (const float4*)sW;
#pragma unroll 4
  for (int k = 0; k < DD; ++k) {
    float hk = hn[k];
#pragma unroll
    for (int q = 0; q < 8; ++q) {
      float4 w = sW4[k*8 + q];
      h[4*q+0] += hk*w.x; h[4*q+1] += hk*w.y;
      h[4*q+2] += hk*w.z; h[4*q+3] += hk*w.w;
    }
  }
#pragma unroll
  for (int d = 0; d < DD; ++d) {
    float s = fmaxf(h[d], 0.f);
#pragma unroll
    for (int off = 32; off > 0; off >>= 1) s += __shfl_xor(s, off);
    if (threadIdx.x == 0) atomicAdd(&stats[64 + d], s);
  }
}

// ---------------- K5: out = (pool/N)@Wf + bf
__global__ void k_fc(const float* __restrict__ stats, const float* __restrict__ Wf,
                     const float* __restrict__ bf, float* __restrict__ out) {
  int o = threadIdx.x;
  if (o < 16) {
    float acc = bf[o];
#pragma unroll
    for (int d = 0; d < DD; ++d)
      acc += stats[64 + d] * (1.0f / NN) * Wf[d * 16 + o];
    out[o] = acc;
  }
}

extern "C" void kernel_launch(void* const* d_in, const int* in_sizes, int n_in,
                              void* d_out, int out_size, void* d_ws, size_t ws_size,
                              hipStream_t stream) {
  const float* x     = (const float*)d_in[0];
  const int*   adj   = (const int*)d_in[1];
  const float* W1    = (const float*)d_in[2];
  const float* b1    = (const float*)d_in[3];
  const float* gamma = (const float*)d_in[4];
  const float* beta  = (const float*)d_in[5];
  const float* W2    = (const float*)d_in[6];
  const float* b2    = (const float*)d_in[7];
  const float* Wf    = (const float*)d_in[8];
  const float* bf    = (const float*)d_in[9];
  float* out = (float*)d_out;

  // ws layout: stats[256] | agg[N*32] | h1[N*32]
  float* stats = (float*)d_ws;
  float* agg = stats + 256;
  float* h1 = agg + (size_t)NN * DD;

  // one memset covers stats + agg (contiguous)
  (void)hipMemsetAsync(d_ws, 0, (256 + (size_t)NN * DD) * sizeof(float), stream);

  dim3 g1(NN / (TPB1 * 4), NN / ROWS_PER_BLK);  // (16, 64) = 1024 blocks
  k_agg<<<g1, TPB1, 0, stream>>>(adj, x, agg);
  k_mlp1<<<NN / TPB2, TPB2, 0, stream>>>(x, agg, W1, b1, h1, stats);
  k_bn<<<1, 64, 0, stream>>>(gamma, beta, stats);
  k_mlp2<<<NN / TPB2, TPB2, 0, stream>>>(h1, W2, b2, stats);
  k_fc<<<1, 64, 0, stream>>>(stats, Wf, bf, out);
}

// Round 4
// 1507.456 us; speedup vs baseline: 1.5848x; 1.5848x over previous
//
#include <hip/hip_runtime.h>

#define NN 16384
#define DD 32
#define TPB1 256
#define NCHUNK 16
#define JCH (NN / NCHUNK)   // 1024 rows per chunk
#define UNROLL 16
#define TPB2 64

// ---------------- K1: part[c][i][:] = sum_{j in chunk c, adj[j][i]!=0} x[j][:]
// Lane owns one column i; scans JCH rows with 16-deep nontemporal dword loads.
// No atomics: register accumulator, one contiguous partial write per chunk.
__global__ __launch_bounds__(TPB1, 4) void k_agg(const int* __restrict__ adj,
                                                 const float* __restrict__ x,
                                                 float* __restrict__ part) {
  const int i = blockIdx.x * TPB1 + threadIdx.x;   // column (dst node)
  const int c = blockIdx.y;                        // row chunk
  const size_t j0 = (size_t)c * JCH;
  float acc[DD];
#pragma unroll
  for (int d = 0; d < DD; ++d) acc[d] = 0.f;
  const int* p = adj + j0 * NN + i;
  for (int jj = 0; jj < JCH; jj += UNROLL) {
    int v[UNROLL];
#pragma unroll
    for (int u = 0; u < UNROLL; ++u)
      v[u] = __builtin_nontemporal_load(p + (size_t)u * NN);
    p += (size_t)UNROLL * NN;
#pragma unroll
    for (int u = 0; u < UNROLL; ++u) {
      if (v[u]) {                      // wave-level taken ~12% per row
        const float4* xr = (const float4*)(x + (j0 + jj + u) * DD);
#pragma unroll
        for (int q = 0; q < 8; ++q) {
          float4 xv = xr[q];
          acc[4*q+0] += xv.x; acc[4*q+1] += xv.y;
          acc[4*q+2] += xv.z; acc[4*q+3] += xv.w;
        }
      }
    }
  }
  float4* dst = (float4*)(part + ((size_t)c * NN + i) * DD);
#pragma unroll
  for (int q = 0; q < 8; ++q)
    dst[q] = make_float4(acc[4*q], acc[4*q+1], acc[4*q+2], acc[4*q+3]);
}

// ---------------- K2: h1 = (x + sum_c part)@W1 + b1; BN sum/sumsq via butterfly + atomics
__global__ __launch_bounds__(TPB2) void k_mlp1(const float* __restrict__ x,
                                               const float* __restrict__ part,
                                               const float* __restrict__ W1,
                                               const float* __restrict__ b1,
                                               float* __restrict__ h1,
                                               float* __restrict__ stats) {
  __shared__ float sW[DD * DD];
  __shared__ float sb[DD];
  for (int t = threadIdx.x; t < DD * DD; t += TPB2) sW[t] = W1[t];
  if (threadIdx.x < DD) sb[threadIdx.x] = b1[threadIdx.x];
  __syncthreads();
  const int i = blockIdx.x * TPB2 + threadIdx.x;
  float hin[DD];
  const float4* xr = (const float4*)(x + (size_t)i * DD);
#pragma unroll
  for (int q = 0; q < 8; ++q) {
    float4 v = xr[q];
    hin[4*q] = v.x; hin[4*q+1] = v.y; hin[4*q+2] = v.z; hin[4*q+3] = v.w;
  }
  for (int c = 0; c < NCHUNK; ++c) {
    const float4* pr = (const float4*)(part + ((size_t)c * NN + i) * DD);
#pragma unroll
    for (int q = 0; q < 8; ++q) {
      float4 v = pr[q];
      hin[4*q] += v.x; hin[4*q+1] += v.y; hin[4*q+2] += v.z; hin[4*q+3] += v.w;
    }
  }
  float h[DD];
#pragma unroll
  for (int d = 0; d < DD; ++d) h[d] = sb[d];
  const float4* sW4 = (const float4*)sW;
#pragma unroll 4
  for (int k = 0; k < DD; ++k) {
    float hk = hin[k];
#pragma unroll
    for (int q = 0; q < 8; ++q) {
      float4 w = sW4[k*8 + q];
      h[4*q+0] += hk*w.x; h[4*q+1] += hk*w.y;
      h[4*q+2] += hk*w.z; h[4*q+3] += hk*w.w;
    }
  }
  float4* hw = (float4*)(h1 + (size_t)i * DD);
#pragma unroll
  for (int q = 0; q < 8; ++q)
    hw[q] = make_float4(h[4*q], h[4*q+1], h[4*q+2], h[4*q+3]);
#pragma unroll
  for (int d = 0; d < DD; ++d) {
    float s = h[d], ss = h[d] * h[d];
#pragma unroll
    for (int off = 32; off > 0; off >>= 1) {
      s += __shfl_xor(s, off);
      ss += __shfl_xor(ss, off);
    }
    if (threadIdx.x == 0) {
      atomicAdd(&stats[d], s);
      atomicAdd(&stats[DD + d], ss);
    }
  }
}

// ---------------- K3: fold BN stats into scale/shift
__global__ void k_bn(const float* __restrict__ gamma, const float* __restrict__ beta,
                     float* __restrict__ stats) {
  int d = threadIdx.x;
  if (d < DD) {
    float mu = stats[d] * (1.0f / NN);
    float var = stats[DD + d] * (1.0f / NN) - mu * mu;
    float sc = gamma[d] * rsqrtf(var + 1e-5f);
    stats[96 + d] = sc;                 // scale
    stats[128 + d] = beta[d] - mu * sc; // shift
  }
}

// ---------------- K4: hn = relu(h1*sc+sh); h2 = relu(hn@W2+b2); pool += sum(h2)
__global__ __launch_bounds__(TPB2) void k_mlp2(const float* __restrict__ h1,
                                               const float* __restrict__ W2,
                                               const float* __restrict__ b2,
                                               float* __restrict__ stats) {
  __shared__ float sW[DD * DD];
  __shared__ float sb[DD], ssc[DD], ssh[DD];
  for (int t = threadIdx.x; t < DD * DD; t += TPB2) sW[t] = W2[t];
  if (threadIdx.x < DD) {
    sb[threadIdx.x] = b2[threadIdx.x];
    ssc[threadIdx.x] = stats[96 + threadIdx.x];
    ssh[threadIdx.x] = stats[128 + threadIdx.x];
  }
  __syncthreads();
  const int i = blockIdx.x * TPB2 + threadIdx.x;
  float hn[DD];
  const float4* hr = (const float4*)(h1 + (size_t)i * DD);
#pragma unroll
  for (int q = 0; q < 8; ++q) {
    float4 v = hr[q];
    hn[4*q] = v.x; hn[4*q+1] = v.y; hn[4*q+2] = v.z; hn[4*q+3] = v.w;
  }
#pragma unroll
  for (int d = 0; d < DD; ++d) hn[d] = fmaxf(hn[d] * ssc[d] + ssh[d], 0.f);
  float h[DD];
#pragma unroll
  for (int d = 0; d < DD; ++d) h[d] = sb[d];
  const float4* sW4 = (const float4*)sW;
#pragma unroll 4
  for (int k = 0; k < DD; ++k) {
    float hk = hn[k];
#pragma unroll
    for (int q = 0; q < 8; ++q) {
      float4 w = sW4[k*8 + q];
      h[4*q+0] += hk*w.x; h[4*q+1] += hk*w.y;
      h[4*q+2] += hk*w.z; h[4*q+3] += hk*w.w;
    }
  }
#pragma unroll
  for (int d = 0; d < DD; ++d) {
    float s = fmaxf(h[d], 0.f);
#pragma unroll
    for (int off = 32; off > 0; off >>= 1) s += __shfl_xor(s, off);
    if (threadIdx.x == 0) atomicAdd(&stats[64 + d], s);
  }
}

// ---------------- K5: out = (pool/N)@Wf + bf
__global__ void k_fc(const float* __restrict__ stats, const float* __restrict__ Wf,
                     const float* __restrict__ bf, float* __restrict__ out) {
  int o = threadIdx.x;
  if (o < 16) {
    float acc = bf[o];
#pragma unroll
    for (int d = 0; d < DD; ++d)
      acc += stats[64 + d] * (1.0f / NN) * Wf[d * 16 + o];
    out[o] = acc;
  }
}

extern "C" void kernel_launch(void* const* d_in, const int* in_sizes, int n_in,
                              void* d_out, int out_size, void* d_ws, size_t ws_size,
                              hipStream_t stream) {
  const float* x     = (const float*)d_in[0];
  const int*   adj   = (const int*)d_in[1];
  const float* W1    = (const float*)d_in[2];
  const float* b1    = (const float*)d_in[3];
  const float* gamma = (const float*)d_in[4];
  const float* beta  = (const float*)d_in[5];
  const float* W2    = (const float*)d_in[6];
  const float* b2    = (const float*)d_in[7];
  const float* Wf    = (const float*)d_in[8];
  const float* bf    = (const float*)d_in[9];
  float* out = (float*)d_out;

  // ws layout: stats[256] | h1[N*32] | part[NCHUNK*N*32]  (~34 MB)
  float* stats = (float*)d_ws;
  float* h1 = stats + 256;
  float* part = h1 + (size_t)NN * DD;

  (void)hipMemsetAsync(d_ws, 0, 256 * sizeof(float), stream);  // stats only

  dim3 g1(NN / TPB1, NCHUNK);  // (64, 16) = 1024 blocks, 16 waves/CU
  k_agg<<<g1, TPB1, 0, stream>>>(adj, x, part);
  k_mlp1<<<NN / TPB2, TPB2, 0, stream>>>(x, part, W1, b1, h1, stats);
  k_bn<<<1, 64, 0, stream>>>(gamma, beta, stats);
  k_mlp2<<<NN / TPB2, TPB2, 0, stream>>>(h1, W2, b2, stats);
  k_fc<<<1, 64, 0, stream>>>(stats, Wf, bf, out);
}